// Round 5
// baseline (444.625 us; speedup 1.0000x reference)
//
#include <hip/hip_runtime.h>
#include <stdint.h>

#define HW 65536
#define BATCH 64
#define KTOP 200
#define TLOW 16.0f      // candidate pre-filter: P(diff >= 16) ~ 4.6% for 2*chi2(3)
#define NBLK_PER_B 64   // phase-A blocks per batch
#define CAP 16384       // dense candidate capacity per batch (mean ~3000)
#define PAD 32          // u32 padding stride (128 B) for contended counters

// ---------------------------------------------------------------------------
// Shared radix-select pass. Requires in scope: n, tid, lane, wave, hist, sufx,
// bcast, wtmp, k_need, getv. Exact MSB-first 2048-bin histogram + suffix scan.
// ---------------------------------------------------------------------------
#define RUN_PASS(BIN_EXPR, PRED_EXPR, OUT_B)                                   \
{                                                                              \
    for (int i2 = tid; i2 < 2048; i2 += 256) hist[i2] = 0;                     \
    __syncthreads();                                                           \
    for (uint32_t i = tid; i < n; i += 256) {                                  \
        uint32_t uv = __float_as_uint(getv(i));                                \
        (void)uv;                                                              \
        if (PRED_EXPR) atomicAdd(&hist[(BIN_EXPR)], 1u);                       \
    }                                                                          \
    __syncthreads();                                                           \
    uint32_t loc[8];                                                           \
    {                                                                          \
        int base8 = tid * 8;                                                   \
        uint32_t run = 0;                                                      \
        for (int j = 7; j >= 0; --j) { run += hist[base8 + j]; loc[j] = run; } \
    }                                                                          \
    uint32_t tot = loc[0];                                                     \
    uint32_t scan = tot;                                                       \
    for (int off = 1; off < 64; off <<= 1) {                                   \
        uint32_t v = __shfl_down(scan, off, 64);                               \
        if (lane + off < 64) scan += v;                                        \
    }                                                                          \
    if (lane == 0) wtmp[wave] = scan;                                          \
    __syncthreads();                                                           \
    uint32_t wabove = 0;                                                       \
    for (int w = wave + 1; w < 4; ++w) wabove += wtmp[w];                      \
    uint32_t add = (scan - tot) + wabove;                                      \
    {                                                                          \
        int base8 = tid * 8;                                                   \
        for (int j = 0; j < 8; ++j) sufx[base8 + j] = loc[j] + add;            \
    }                                                                          \
    __syncthreads();                                                           \
    {                                                                          \
        int base8 = tid * 8;                                                   \
        for (int j = 0; j < 8; ++j) {                                          \
            int i2 = base8 + j;                                                \
            uint32_t Si = sufx[i2];                                            \
            uint32_t Sn = (i2 + 1 < 2048) ? sufx[i2 + 1] : 0;                  \
            if (Si >= k_need && Sn < k_need) {                                 \
                bcast[0] = (uint32_t)i2;                                       \
                bcast[1] = k_need - Sn;                                        \
            }                                                                  \
        }                                                                      \
    }                                                                          \
    __syncthreads();                                                           \
    OUT_B  = bcast[0];                                                         \
    k_need = bcast[1];                                                         \
    __syncthreads();                                                           \
}

// ---------------------------------------------------------------------------
// Kernel 0: zero the contended counters (cnt, done, fin). 4128 words.
// ---------------------------------------------------------------------------
__global__ void init_kernel(uint32_t* __restrict__ p)
{
    const int total = BATCH * PAD * 2 + PAD;
    for (int i = blockIdx.x * 256 + threadIdx.x; i < total; i += 256 * gridDim.x)
        p[i] = 0;
}

// ---------------------------------------------------------------------------
// Mega kernel: phase A (diff + compact to dense per-batch region), then the
// last-arriving block per batch runs phase B (exact radix select + sum), and
// the last selector computes the grand mean. Device-scope atomics + fences
// only — no dispatch-order or co-residency assumptions.
// ---------------------------------------------------------------------------
__global__ __launch_bounds__(256) void fused_all(
    const float* __restrict__ pred,
    const float* __restrict__ target,
    float* __restrict__ cand,        // [BATCH][CAP]
    uint32_t* __restrict__ cnt,      // [BATCH*PAD]
    uint32_t* __restrict__ done,     // [BATCH*PAD]
    uint32_t* __restrict__ fin,      // [1]
    float* __restrict__ partials,    // [BATCH]
    float* __restrict__ out)
{
    __shared__ uint32_t smem[4096];  // phase A: sbuf(1024 f32); phase B: hist|sufx
    __shared__ uint32_t scnt, sbase_s, rank_s, nsh;
    __shared__ uint32_t bcast[2];
    __shared__ uint32_t wtmp[4];
    __shared__ float    wsumS[4];
    __shared__ uint32_t wcntS[4];

    const int tid  = threadIdx.x;
    const int lane = tid & 63;
    const int wave = tid >> 6;
    const int b    = blockIdx.x >> 6;
    const int blk  = blockIdx.x & 63;

    float* sbuf = (float*)smem;
    if (tid == 0) scnt = 0;
    __syncthreads();

    // ---------------- phase A: diff + compact ----------------
    {
        const int i = blk * 256 + tid;                 // float4 index within batch
        const float4* p = (const float4*)pred;
        const float4* t = (const float4*)target;
        long base = (long)b * 49152 + i;               // 3 * 16384
        float4 p0 = p[base], p1 = p[base + 16384], p2 = p[base + 32768];
        float4 t0 = t[base], t1 = t[base + 16384], t2 = t[base + 32768];

        float d[4];
        {
            float a0 = t0.x - p0.x, a1 = t1.x - p1.x, a2 = t2.x - p2.x;
            d[0] = a0 * a0 + a1 * a1 + a2 * a2;
        }
        {
            float a0 = t0.y - p0.y, a1 = t1.y - p1.y, a2 = t2.y - p2.y;
            d[1] = a0 * a0 + a1 * a1 + a2 * a2;
        }
        {
            float a0 = t0.z - p0.z, a1 = t1.z - p1.z, a2 = t2.z - p2.z;
            d[2] = a0 * a0 + a1 * a1 + a2 * a2;
        }
        {
            float a0 = t0.w - p0.w, a1 = t1.w - p1.w, a2 = t2.w - p2.w;
            d[3] = a0 * a0 + a1 * a1 + a2 * a2;
        }

        #pragma unroll
        for (int j = 0; j < 4; ++j) {
            bool pr = d[j] >= TLOW;
            unsigned long long mask = __ballot(pr);
            if (mask) {                                   // wave-uniform
                uint32_t c = (uint32_t)__popcll(mask);
                uint32_t wb = 0;
                if (lane == 0) wb = atomicAdd(&scnt, c);  // LDS atomic (on-CU)
                wb = __shfl(wb, 0, 64);
                if (pr) {
                    uint32_t rank = (uint32_t)__popcll(mask & ((1ull << lane) - 1ull));
                    sbuf[wb + rank] = d[j];
                }
            }
        }
        __syncthreads();

        const uint32_t nloc = scnt;
        if (tid == 0) sbase_s = atomicAdd(&cnt[b * PAD], nloc);  // 1 global atomic/block
        __syncthreads();
        const uint32_t bs = sbase_s;
        float* cb = cand + (long)b * CAP;
        for (uint32_t k = tid; k < nloc; k += 256)
            if (bs + k < CAP) cb[bs + k] = sbuf[k];
    }

    __threadfence();                                     // release cand writes
    if (tid == 0) rank_s = atomicAdd(&done[b * PAD], 1u);
    __syncthreads();
    if (rank_s != NBLK_PER_B - 1) return;                // 63/64 blocks exit

    // ---------------- phase B: last block of batch b selects ----------------
    __threadfence();                                     // acquire
    if (tid == 0) nsh = cnt[b * PAD];
    __syncthreads();

    const uint32_t total = nsh;
    const bool fb = (total < KTOP) || (total > CAP);     // never in practice
    const uint32_t n = fb ? HW : total;
    const float* dsrc = cand + (long)b * CAP;
    const float* pb = pred   + (long)b * 3 * HW;
    const float* tb = target + (long)b * 3 * HW;

    auto getv = [&](uint32_t idx) -> float {
        if (!fb) return dsrc[idx];
        float a0 = tb[idx] - pb[idx];
        float a1 = tb[HW + idx] - pb[HW + idx];
        float a2 = tb[2 * HW + idx] - pb[2 * HW + idx];
        return a0 * a0 + a1 * a1 + a2 * a2;
    };

    uint32_t* hist = smem;
    uint32_t* sufx = smem + 2048;
    uint32_t k_need = KTOP;
    uint32_t b1 = 0, b2 = 0, b3 = 0;

    RUN_PASS((uv >> 21), true, b1)
    RUN_PASS(((uv >> 10) & 0x7FFu), ((uv >> 21) == b1), b2)
    {
        uint32_t prefix21 = (b1 << 11) | b2;
        RUN_PASS((uv & 0x3FFu), ((uv >> 10) == prefix21), b3)
    }

    const uint32_t T  = (b1 << 21) | (b2 << 10) | b3;
    const float    tv = __uint_as_float(T);

    float    s = 0.0f;
    uint32_t c = 0;
    for (uint32_t i = tid; i < n; i += 256) {
        uint32_t uv = __float_as_uint(getv(i));
        if (uv > T) { s += __uint_as_float(uv); c += 1u; }
    }
    for (int off = 32; off > 0; off >>= 1) {
        s += __shfl_down(s, off, 64);
        c += __shfl_down(c, off, 64);
    }
    if (lane == 0) { wsumS[wave] = s; wcntS[wave] = c; }
    __syncthreads();
    if (tid == 0) {
        float    S = 0.0f;
        uint32_t C = 0;
        for (int w = 0; w < 4; ++w) { S += wsumS[w]; C += wcntS[w]; }
        partials[b] = S + (float)(KTOP - C) * tv;
    }

    // ---------------- grand finalize: last selector computes the mean -------
    __threadfence();
    if (tid == 0) rank_s = atomicAdd(fin, 1u);
    __syncthreads();
    if (rank_s != BATCH - 1) return;
    __threadfence();
    if (tid < 64) {
        float v = partials[tid];
        for (int off = 32; off > 0; off >>= 1)
            v += __shfl_down(v, off, 64);
        if (tid == 0) out[0] = v / (float)(BATCH * KTOP);
    }
}

// ---------------------------------------------------------------------------
// Fallback (ws too small): exact full-row select per batch + finalize.
// ---------------------------------------------------------------------------
__global__ __launch_bounds__(256) void select_full(
    const float* __restrict__ pred,
    const float* __restrict__ target,
    float* __restrict__ partials)
{
    __shared__ uint32_t hist[2048];
    __shared__ uint32_t sufx[2048];
    __shared__ uint32_t bcast[2];
    __shared__ uint32_t wtmp[4];
    __shared__ float    wsumS[4];
    __shared__ uint32_t wcntS[4];

    const int b    = blockIdx.x;
    const int tid  = threadIdx.x;
    const int lane = tid & 63;
    const int wave = tid >> 6;
    const uint32_t n = HW;

    const float* pb = pred   + (long)b * 3 * HW;
    const float* tb = target + (long)b * 3 * HW;
    auto getv = [&](uint32_t idx) -> float {
        float a0 = tb[idx] - pb[idx];
        float a1 = tb[HW + idx] - pb[HW + idx];
        float a2 = tb[2 * HW + idx] - pb[2 * HW + idx];
        return a0 * a0 + a1 * a1 + a2 * a2;
    };

    uint32_t k_need = KTOP;
    uint32_t b1 = 0, b2 = 0, b3 = 0;
    RUN_PASS((uv >> 21), true, b1)
    RUN_PASS(((uv >> 10) & 0x7FFu), ((uv >> 21) == b1), b2)
    {
        uint32_t prefix21 = (b1 << 11) | b2;
        RUN_PASS((uv & 0x3FFu), ((uv >> 10) == prefix21), b3)
    }

    const uint32_t T  = (b1 << 21) | (b2 << 10) | b3;
    const float    tv = __uint_as_float(T);
    float    s = 0.0f;
    uint32_t c = 0;
    for (uint32_t i = tid; i < n; i += 256) {
        uint32_t uv = __float_as_uint(getv(i));
        if (uv > T) { s += __uint_as_float(uv); c += 1u; }
    }
    for (int off = 32; off > 0; off >>= 1) {
        s += __shfl_down(s, off, 64);
        c += __shfl_down(c, off, 64);
    }
    if (lane == 0) { wsumS[wave] = s; wcntS[wave] = c; }
    __syncthreads();
    if (tid == 0) {
        float    S = 0.0f;
        uint32_t C = 0;
        for (int w = 0; w < 4; ++w) { S += wsumS[w]; C += wcntS[w]; }
        partials[b] = S + (float)(KTOP - C) * tv;
    }
}

__global__ void finalize_kernel(const float* __restrict__ partials,
                                float* __restrict__ out)
{
    float v = partials[threadIdx.x];
    for (int off = 32; off > 0; off >>= 1)
        v += __shfl_down(v, off, 64);
    if (threadIdx.x == 0)
        out[0] = v / (float)(BATCH * KTOP);
}

extern "C" void kernel_launch(void* const* d_in, const int* in_sizes, int n_in,
                              void* d_out, int out_size, void* d_ws, size_t ws_size,
                              hipStream_t stream)
{
    const float* pred   = (const float*)d_in[0];
    const float* target = (const float*)d_in[1];
    float* out = (float*)d_out;

    uint32_t* cnt      = (uint32_t*)d_ws;                 // [BATCH*PAD]  8 KB
    uint32_t* done     = cnt + BATCH * PAD;               // [BATCH*PAD]  8 KB
    uint32_t* fin      = done + BATCH * PAD;              // [PAD]        128 B
    float*    partials = (float*)(fin + PAD);             // [BATCH]      256 B
    float*    cand     = (float*)((char*)d_ws + 32768);   // [BATCH][CAP] 4 MB
    const size_t need  = 32768 + (size_t)BATCH * CAP * sizeof(float);

    if (ws_size >= need) {
        init_kernel<<<4, 256, 0, stream>>>((uint32_t*)d_ws);
        fused_all<<<BATCH * NBLK_PER_B, 256, 0, stream>>>(
            pred, target, cand, cnt, done, fin, partials, out);
    } else {
        select_full<<<BATCH, 256, 0, stream>>>(pred, target, partials);
        finalize_kernel<<<1, 64, 0, stream>>>(partials, out);
    }
}

// Round 6
// 38.969 us; speedup vs baseline: 11.4099x; 11.4099x over previous
//
#include <hip/hip_runtime.h>
#include <stdint.h>

#define HW 65536
#define BATCH 64
#define KTOP 200
#define TLOW 16.0f        // candidate pre-filter: P(diff >= 16) ~ 4.6% for 2*chi2(3)
#define K1_BLOCKS 1024    // 16 blocks per batch, 4096 elements per block
#define NSLOT 128         // candidate slots per WAVE (1024 elems/wave, mean ~47, 12 sigma)
#define SLOTS_PER_B 64    // 16 blocks * 4 waves
#define CLS_MAX 8192      // 64 slots * 128 = max candidates per batch

// ---------------------------------------------------------------------------
// Kernel 1: diff + per-wave candidate compaction. No LDS, no barriers, no
// atomics. Each wave owns a private slot region; running count tracked in
// registers via wave-uniform ballot/popcount. Also zeroes out[0] for K2.
// ---------------------------------------------------------------------------
__global__ __launch_bounds__(256) void diff_compact(
    const float* __restrict__ pred,
    const float* __restrict__ target,
    float* __restrict__ cand,        // [K1_BLOCKS*4][NSLOT]
    uint32_t* __restrict__ bcnt,     // [K1_BLOCKS*4]
    float* __restrict__ out)
{
    const int tid  = threadIdx.x;
    const int lane = tid & 63;
    const int wave = tid >> 6;
    const int b    = blockIdx.x >> 4;        // 16 blocks per batch
    const int blk  = blockIdx.x & 15;
    const int slot = blockIdx.x * 4 + wave;  // global wave-slot id

    if (blockIdx.x == 0 && tid == 0) out[0] = 0.0f;   // K2 accumulates into out

    const float4* p = (const float4*)pred;
    const float4* t = (const float4*)target;
    const long bb = (long)b * 49152;         // 3 * 16384 float4 per batch
    float* cs = cand + (long)slot * NSLOT;

    const unsigned long long lmask = (lane == 63) ? ~0ull : ((1ull << (lane + 1)) - 1ull);
    uint32_t wcount = 0;

    #pragma unroll
    for (int chunk = 0; chunk < 4; ++chunk) {
        const int pos = blk * 1024 + chunk * 256 + tid;   // float4 index in batch
        long base = bb + pos;
        float4 p0 = p[base], p1 = p[base + 16384], p2 = p[base + 32768];
        float4 t0 = t[base], t1 = t[base + 16384], t2 = t[base + 32768];

        float d[4];
        {
            float a0 = t0.x - p0.x, a1 = t1.x - p1.x, a2 = t2.x - p2.x;
            d[0] = a0 * a0 + a1 * a1 + a2 * a2;
        }
        {
            float a0 = t0.y - p0.y, a1 = t1.y - p1.y, a2 = t2.y - p2.y;
            d[1] = a0 * a0 + a1 * a1 + a2 * a2;
        }
        {
            float a0 = t0.z - p0.z, a1 = t1.z - p1.z, a2 = t2.z - p2.z;
            d[2] = a0 * a0 + a1 * a1 + a2 * a2;
        }
        {
            float a0 = t0.w - p0.w, a1 = t1.w - p1.w, a2 = t2.w - p2.w;
            d[3] = a0 * a0 + a1 * a1 + a2 * a2;
        }

        #pragma unroll
        for (int j = 0; j < 4; ++j) {
            bool pr = d[j] >= TLOW;
            unsigned long long mask = __ballot(pr);
            if (pr) {
                uint32_t idx = wcount + (uint32_t)__popcll(mask & lmask) - 1u;
                if (idx < NSLOT) cs[idx] = d[j];
            }
            wcount += (uint32_t)__popcll(mask);   // wave-uniform
        }
    }
    if (lane == 0) bcnt[slot] = wcount;           // raw count; >NSLOT -> K2 fallback
}

// ---------------------------------------------------------------------------
// Shared radix-pass macros. Exact MSB-first 2048-bin histogram + suffix scan.
// RUN_PASS2: 2-copy replicated histogram (K2). RUN_PASS1: single copy.
// ---------------------------------------------------------------------------
#define RUN_PASS2(BIN_EXPR, PRED_EXPR, OUT_B)                                  \
{                                                                              \
    for (int i2 = tid; i2 < 4096; i2 += 256) histF[i2] = 0;                    \
    __syncthreads();                                                           \
    uint32_t* myh = histF + ((wave & 1) << 11);                                \
    for (uint32_t i = tid; i < n; i += 256) {                                  \
        uint32_t uv = __float_as_uint(getv(i));                                \
        (void)uv;                                                              \
        if (PRED_EXPR) atomicAdd(&myh[(BIN_EXPR)], 1u);                        \
    }                                                                          \
    __syncthreads();                                                           \
    uint32_t loc[8];                                                           \
    {                                                                          \
        int base8 = tid * 8;                                                   \
        uint32_t run = 0;                                                      \
        for (int j = 7; j >= 0; --j) {                                         \
            run += histF[base8 + j] + histF[2048 + base8 + j];                 \
            loc[j] = run;                                                      \
        }                                                                      \
    }                                                                          \
    SCAN_TAIL(OUT_B)                                                           \
}

#define RUN_PASS1(BIN_EXPR, PRED_EXPR, OUT_B)                                  \
{                                                                              \
    for (int i2 = tid; i2 < 2048; i2 += 256) histF[i2] = 0;                    \
    __syncthreads();                                                           \
    for (uint32_t i = tid; i < n; i += 256) {                                  \
        uint32_t uv = __float_as_uint(getv(i));                                \
        (void)uv;                                                              \
        if (PRED_EXPR) atomicAdd(&histF[(BIN_EXPR)], 1u);                      \
    }                                                                          \
    __syncthreads();                                                           \
    uint32_t loc[8];                                                           \
    {                                                                          \
        int base8 = tid * 8;                                                   \
        uint32_t run = 0;                                                      \
        for (int j = 7; j >= 0; --j) { run += histF[base8 + j]; loc[j] = run; }\
    }                                                                          \
    SCAN_TAIL(OUT_B)                                                           \
}

#define SCAN_TAIL(OUT_B)                                                       \
    uint32_t tot = loc[0];                                                     \
    uint32_t scan = tot;                                                       \
    for (int off = 1; off < 64; off <<= 1) {                                   \
        uint32_t v = __shfl_down(scan, off, 64);                               \
        if (lane + off < 64) scan += v;                                        \
    }                                                                          \
    if (lane == 0) wtmp[wave] = scan;                                          \
    __syncthreads();                                                           \
    uint32_t wabove = 0;                                                       \
    for (int w = wave + 1; w < 4; ++w) wabove += wtmp[w];                      \
    uint32_t add = (scan - tot) + wabove;                                      \
    {                                                                          \
        int base8 = tid * 8;                                                   \
        for (int j = 0; j < 8; ++j) sufx[base8 + j] = loc[j] + add;            \
    }                                                                          \
    __syncthreads();                                                           \
    {                                                                          \
        int base8 = tid * 8;                                                   \
        for (int j = 0; j < 8; ++j) {                                          \
            int i2 = base8 + j;                                                \
            uint32_t Si = sufx[i2];                                            \
            uint32_t Sn = (i2 + 1 < 2048) ? sufx[i2 + 1] : 0;                  \
            if (Si >= k_need && Sn < k_need) {                                 \
                bcast[0] = (uint32_t)i2;                                       \
                bcast[1] = k_need - Sn;                                        \
            }                                                                  \
        }                                                                      \
    }                                                                          \
    __syncthreads();                                                           \
    OUT_B  = bcast[0];                                                         \
    k_need = bcast[1];                                                         \
    __syncthreads();

// ---------------------------------------------------------------------------
// Kernel 2: one block per batch. Gather candidates from the 64 wave-slots
// into LDS, exact 3-pass radix select + top-KTOP sum, atomicAdd scaled
// partial into out. Fallback: exact full-row recompute.
// ---------------------------------------------------------------------------
__global__ __launch_bounds__(256) void select_sum(
    const float* __restrict__ cand,
    const uint32_t* __restrict__ bcnt,
    const float* __restrict__ pred,
    const float* __restrict__ target,
    float* __restrict__ out)
{
    __shared__ float    cls[CLS_MAX];     // 32 KB
    __shared__ uint32_t hist2[4096];      // 16 KB (2 copies)
    __shared__ uint32_t sufx[2048];       // 8 KB
    __shared__ uint32_t scounts[64];
    __shared__ uint32_t soff[64];
    __shared__ uint32_t meta[2];
    __shared__ uint32_t bcast[2];
    __shared__ uint32_t wtmp[4];
    __shared__ float    wsumS[4];
    __shared__ uint32_t wcntS[4];

    const int b    = blockIdx.x;
    const int tid  = threadIdx.x;
    const int lane = tid & 63;
    const int wave = tid >> 6;
    uint32_t* histF = hist2;

    // counts + exclusive scan (wave 0 only; 64 slots per batch, contiguous)
    if (tid < 64) {
        uint32_t c = bcnt[b * SLOTS_PER_B + tid];
        scounts[tid] = c;
        uint32_t scan = c;
        for (int off = 1; off < 64; off <<= 1) {
            uint32_t v = __shfl_up(scan, off, 64);
            if (lane >= off) scan += v;
        }
        soff[tid] = scan - c;
        if (tid == 63) meta[0] = scan;
        uint32_t ovf = __ballot(c > NSLOT) ? 1u : 0u;
        if (tid == 0) meta[1] = ovf;
    }
    __syncthreads();

    const uint32_t total = meta[0];
    const bool fb = (meta[1] != 0) || (total < KTOP);
    const uint32_t n = fb ? HW : total;

    if (!fb) {
        for (int j = wave; j < 64; j += 4) {
            uint32_t c   = scounts[j];
            uint32_t off = soff[j];
            const float* src = cand + (long)(b * SLOTS_PER_B + j) * NSLOT;
            for (uint32_t k = lane; k < c; k += 64)
                cls[off + k] = src[k];
        }
    }
    __syncthreads();

    const float* pb = pred   + (long)b * 3 * HW;
    const float* tb = target + (long)b * 3 * HW;
    auto getv = [&](uint32_t idx) -> float {
        if (!fb) return cls[idx];
        float a0 = tb[idx] - pb[idx];
        float a1 = tb[HW + idx] - pb[HW + idx];
        float a2 = tb[2 * HW + idx] - pb[2 * HW + idx];
        return a0 * a0 + a1 * a1 + a2 * a2;
    };

    uint32_t k_need = KTOP;
    uint32_t b1 = 0, b2 = 0, b3 = 0;

    RUN_PASS2((uv >> 21), true, b1)
    RUN_PASS2(((uv >> 10) & 0x7FFu), ((uv >> 21) == b1), b2)
    {
        uint32_t prefix21 = (b1 << 11) | b2;
        RUN_PASS2((uv & 0x3FFu), ((uv >> 10) == prefix21), b3)
    }

    const uint32_t T  = (b1 << 21) | (b2 << 10) | b3;
    const float    tv = __uint_as_float(T);

    float    s = 0.0f;
    uint32_t c = 0;
    for (uint32_t i = tid; i < n; i += 256) {
        uint32_t uv = __float_as_uint(getv(i));
        if (uv > T) { s += __uint_as_float(uv); c += 1u; }
    }
    for (int off = 32; off > 0; off >>= 1) {
        s += __shfl_down(s, off, 64);
        c += __shfl_down(c, off, 64);
    }
    if (lane == 0) { wsumS[wave] = s; wcntS[wave] = c; }
    __syncthreads();
    if (tid == 0) {
        float    S = 0.0f;
        uint32_t C = 0;
        for (int w = 0; w < 4; ++w) { S += wsumS[w]; C += wcntS[w]; }
        float partial = S + (float)(KTOP - C) * tv;
        atomicAdd(out, partial * (1.0f / (float)(BATCH * KTOP)));
    }
}

// ---------------------------------------------------------------------------
// Fallback (ws too small): exact full-row select per batch + finalize.
// ---------------------------------------------------------------------------
__global__ __launch_bounds__(256) void select_full(
    const float* __restrict__ pred,
    const float* __restrict__ target,
    float* __restrict__ partials)
{
    __shared__ uint32_t histF[2048];
    __shared__ uint32_t sufx[2048];
    __shared__ uint32_t bcast[2];
    __shared__ uint32_t wtmp[4];
    __shared__ float    wsumS[4];
    __shared__ uint32_t wcntS[4];

    const int b    = blockIdx.x;
    const int tid  = threadIdx.x;
    const int lane = tid & 63;
    const int wave = tid >> 6;
    const uint32_t n = HW;

    const float* pb = pred   + (long)b * 3 * HW;
    const float* tb = target + (long)b * 3 * HW;
    auto getv = [&](uint32_t idx) -> float {
        float a0 = tb[idx] - pb[idx];
        float a1 = tb[HW + idx] - pb[HW + idx];
        float a2 = tb[2 * HW + idx] - pb[2 * HW + idx];
        return a0 * a0 + a1 * a1 + a2 * a2;
    };

    uint32_t k_need = KTOP;
    uint32_t b1 = 0, b2 = 0, b3 = 0;
    RUN_PASS1((uv >> 21), true, b1)
    RUN_PASS1(((uv >> 10) & 0x7FFu), ((uv >> 21) == b1), b2)
    {
        uint32_t prefix21 = (b1 << 11) | b2;
        RUN_PASS1((uv & 0x3FFu), ((uv >> 10) == prefix21), b3)
    }

    const uint32_t T  = (b1 << 21) | (b2 << 10) | b3;
    const float    tv = __uint_as_float(T);
    float    s = 0.0f;
    uint32_t c = 0;
    for (uint32_t i = tid; i < n; i += 256) {
        uint32_t uv = __float_as_uint(getv(i));
        if (uv > T) { s += __uint_as_float(uv); c += 1u; }
    }
    for (int off = 32; off > 0; off >>= 1) {
        s += __shfl_down(s, off, 64);
        c += __shfl_down(c, off, 64);
    }
    if (lane == 0) { wsumS[wave] = s; wcntS[wave] = c; }
    __syncthreads();
    if (tid == 0) {
        float    S = 0.0f;
        uint32_t C = 0;
        for (int w = 0; w < 4; ++w) { S += wsumS[w]; C += wcntS[w]; }
        partials[b] = S + (float)(KTOP - C) * tv;
    }
}

__global__ void finalize_kernel(const float* __restrict__ partials,
                                float* __restrict__ out)
{
    float v = partials[threadIdx.x];
    for (int off = 32; off > 0; off >>= 1)
        v += __shfl_down(v, off, 64);
    if (threadIdx.x == 0)
        out[0] = v / (float)(BATCH * KTOP);
}

extern "C" void kernel_launch(void* const* d_in, const int* in_sizes, int n_in,
                              void* d_out, int out_size, void* d_ws, size_t ws_size,
                              hipStream_t stream)
{
    const float* pred   = (const float*)d_in[0];
    const float* target = (const float*)d_in[1];
    float* out = (float*)d_out;

    const int nslots = K1_BLOCKS * 4;                       // 4096
    uint32_t* bcnt = (uint32_t*)d_ws;                       // 16 KB
    float*    cand = (float*)((char*)d_ws + nslots * 4);    // 2 MB
    const size_t need = (size_t)nslots * 4 + (size_t)nslots * NSLOT * 4;

    if (ws_size >= need) {
        diff_compact<<<K1_BLOCKS, 256, 0, stream>>>(pred, target, cand, bcnt, out);
        select_sum<<<BATCH, 256, 0, stream>>>(cand, bcnt, pred, target, out);
    } else {
        float* partials = (float*)d_ws;                     // 256 B
        select_full<<<BATCH, 256, 0, stream>>>(pred, target, partials);
        finalize_kernel<<<1, 64, 0, stream>>>(partials, out);
    }
}